// Round 1
// 1548.680 us; speedup vs baseline: 1.0204x; 1.0204x over previous
//
#include <hip/hip_runtime.h>

#define H_ 16
#define L_ 4096
#define D_ 64
#define NKT 64   // 64-wide key tiles

typedef __attribute__((ext_vector_type(4))) float    f32x4;
typedef __attribute__((ext_vector_type(8))) short    s16x8;
typedef __attribute__((ext_vector_type(4))) _Float16 h16x4;
typedef __attribute__((ext_vector_type(8))) _Float16 h16x8;

__device__ __forceinline__ short f2bf(float x) {      // fp32 -> bf16 bits, RNE
    unsigned u = __float_as_uint(x);
    u = (u + 0x7fffu + ((u >> 16) & 1u)) >> 16;
    return (short)u;
}
__device__ __forceinline__ float bf2f(short b) {
    return __uint_as_float(((unsigned)(unsigned short)b) << 16);
}

// ---------------- prep: K -> bf16 hi/lo A-fragment streams ----------------
// chunk ((kt*4 + w)*2 + ks), lane l: 8 bf16 =
//   K[kt*64 + 16w + (l&15)][32ks + 8*(l>>4) + j], j=0..7
// so attn loads one wave-coalesced dwordx4 per fragment.
__global__ __launch_bounds__(256) void kfrag_kernel(const float* __restrict__ k,
                                                    short* __restrict__ khi,
                                                    short* __restrict__ klo) {
    __shared__ float tile[64][65];
    const int h = blockIdx.y, kt = blockIdx.x, tid = threadIdx.x;
    {
        const int c = tid & 15, r = tid >> 4;
        const float* src = k + ((size_t)(h * L_ + kt * 64)) * D_;
        for (int i = 0; i < 4; ++i) {
            int n = r + 16 * i;
            f32x4 x = *(const f32x4*)(src + (size_t)n * D_ + c * 4);
            tile[n][c * 4 + 0] = x.x;
            tile[n][c * 4 + 1] = x.y;
            tile[n][c * 4 + 2] = x.z;
            tile[n][c * 4 + 3] = x.w;
        }
    }
    __syncthreads();
    const size_t base = (size_t)(h * NKT + kt) * (8 * 64 * 8);
    for (int e = 0; e < 2; ++e) {
        int idx = tid + 256 * e;
        int l = idx & 63, set = idx >> 6;              // set = w*2 + ks
        int row = 16 * (set >> 1) + (l & 15);
        int col = 32 * (set & 1) + 8 * (l >> 4);
        s16x8 hi, lo;
        #pragma unroll
        for (int j = 0; j < 8; ++j) {
            float x = tile[row][col + j];
            short hb = f2bf(x);
            hi[j] = hb;
            lo[j] = f2bf(x - bf2f(hb));
        }
        *(s16x8*)(khi + base + (size_t)idx * 8) = hi;
        *(s16x8*)(klo + base + (size_t)idx * 8) = lo;
    }
}

// ---------------- prep: V -> fp16 B-fragment stream for 16x16x16f16 PV ----
// chunk ((kt*4 + s)*2 + p), lane l (r=l&15, g=l>>4): 8 halfs =
//   [ V[kt*64+16s+4g+j][32p + r]      j=0..3 ]   (dt = 2p)
//   [ V[kt*64+16s+4g+j][32p + 16 + r] j=0..3 ]   (dt = 2p+1)
__global__ __launch_bounds__(256) void vfrag_kernel(const float* __restrict__ v,
                                                    _Float16* __restrict__ vf) {
    __shared__ float tile[64][65];
    const int h = blockIdx.y, kt = blockIdx.x, tid = threadIdx.x;
    {
        const int c = tid & 15, r = tid >> 4;
        const float* src = v + ((size_t)(h * L_ + kt * 64)) * D_;
        for (int i = 0; i < 4; ++i) {
            int n = r + 16 * i;
            f32x4 x = *(const f32x4*)(src + (size_t)n * D_ + c * 4);
            tile[n][c * 4 + 0] = x.x;
            tile[n][c * 4 + 1] = x.y;
            tile[n][c * 4 + 2] = x.z;
            tile[n][c * 4 + 3] = x.w;
        }
    }
    __syncthreads();
    const size_t base = (size_t)(h * NKT + kt) * (8 * 64 * 8);
    for (int e = 0; e < 2; ++e) {
        int idx = tid + 256 * e;
        int l = idx & 63, set = idx >> 6;              // set = s*2 + p
        int s = set >> 1, p = set & 1;
        int g = l >> 4, r = l & 15;
        h16x8 y;
        #pragma unroll
        for (int j = 0; j < 4; ++j) {
            y[j]     = (_Float16)tile[16 * s + 4 * g + j][32 * p + r];
            y[4 + j] = (_Float16)tile[16 * s + 4 * g + j][32 * p + 16 + r];
        }
        *(h16x8*)(vf + base + (size_t)idx * 8) = y;
    }
}

// fragment offset within a head stream: chunk (kt*8 + w*2 + ks), lane
#define KFO(kt_, ks_) (((size_t)(((kt_) * 8 + w * 2 + (ks_)) * 64 + lane)) * 8)

// one block = one head x 64 query rows; wave w owns key band [16w,16w+16)
// per tile. No LDS, no barriers in either K-loop: K/V fragments are loaded
// straight from pre-tiled global streams (L2-resident), reg double-buffered.
__global__ __launch_bounds__(256, 2) void attn_kernel(
    const float* __restrict__ q,
    const short* __restrict__ khi, const short* __restrict__ klo,
    const _Float16* __restrict__ vf,
    float* __restrict__ out, float* __restrict__ score)
{
    __shared__ float Ored[64][65];
    __shared__ float redM[4][4][16], redL[4][4][16];

    // chunked XCD swizzle: 1024 blocks / 8 XCDs -> 2 heads per XCD (L2 reuse)
    int flat = blockIdx.y * gridDim.x + blockIdx.x;
    flat = (flat & 7) * 128 + (flat >> 3);
    const int h = flat >> 6, qb = flat & 63;

    const int tid = threadIdx.x, w = tid >> 6;
    const int lane = tid & 63, lrow = lane & 15, lgrp = lane >> 4;

    // ---- Q fragments (bf16 hi/lo), built once, held in regs (64 VGPRs) ----
    s16x8 bQh[4][2], bQl[4][2];
    const float* qbase = q + ((size_t)(h * L_ + qb * 64)) * D_;
    #pragma unroll
    for (int mt = 0; mt < 4; ++mt)
        #pragma unroll
        for (int ks = 0; ks < 2; ++ks) {
            const float* p0 = qbase + (size_t)(16 * mt + lrow) * D_ + 32 * ks + 8 * lgrp;
            f32x4 a = *(const f32x4*)p0;
            f32x4 b = *(const f32x4*)(p0 + 4);
            float xs[8] = {a.x, a.y, a.z, a.w, b.x, b.y, b.z, b.w};
            s16x8 hi, lo;
            #pragma unroll
            for (int j = 0; j < 8; ++j) {
                float x = xs[j] * 0.125f;               // 1/sqrt(64)
                short hb = f2bf(x);
                hi[j] = hb;
                lo[j] = f2bf(x - bf2f(hb));
            }
            bQh[mt][ks] = hi;
            bQl[mt][ks] = lo;
        }

    const size_t hoff = (size_t)h * (L_ * D_);
    const short*    khs = khi + hoff;
    const short*    kls = klo + hoff;
    const _Float16* vfs = vf + hoff;

    // ---------- phase 1: per-lane online stats over all 4096 keys ----------
    float M[4], Ls[4];
    #pragma unroll
    for (int mt = 0; mt < 4; ++mt) { M[mt] = -1e30f; Ls[mt] = 0.f; }

    s16x8 kh[2], kl[2];
    #pragma unroll
    for (int ks = 0; ks < 2; ++ks) {
        kh[ks] = *(const s16x8*)(khs + KFO(0, ks));
        kl[ks] = *(const s16x8*)(kls + KFO(0, ks));
    }
    #pragma unroll 2
    for (int kt = 0; kt < NKT; ++kt) {
        s16x8 nkh[2], nkl[2];
        const int ktn = (kt + 1) & 63;                  // wrap: harmless prefetch
        #pragma unroll
        for (int ks = 0; ks < 2; ++ks) {
            nkh[ks] = *(const s16x8*)(khs + KFO(ktn, ks));
            nkl[ks] = *(const s16x8*)(kls + KFO(ktn, ks));
        }
        #pragma unroll
        for (int mt = 0; mt < 4; ++mt) {
            f32x4 acc = {0.f, 0.f, 0.f, 0.f};
            #pragma unroll
            for (int ks = 0; ks < 2; ++ks) {
                acc = __builtin_amdgcn_mfma_f32_16x16x32_bf16(kh[ks], bQh[mt][ks], acc, 0, 0, 0);
                acc = __builtin_amdgcn_mfma_f32_16x16x32_bf16(kh[ks], bQl[mt][ks], acc, 0, 0, 0);
                acc = __builtin_amdgcn_mfma_f32_16x16x32_bf16(kl[ks], bQh[mt][ks], acc, 0, 0, 0);
            }
            // lane-local online update (no cross-lane shuffles in the loop)
            float tm = fmaxf(fmaxf(acc.x, acc.y), fmaxf(acc.z, acc.w));
            float nM = fmaxf(M[mt], tm);
            float s = __expf(acc.x - nM) + __expf(acc.y - nM)
                    + __expf(acc.z - nM) + __expf(acc.w - nM);
            Ls[mt] = Ls[mt] * __expf(M[mt] - nM) + s;
            M[mt] = nM;
        }
        kh[0] = nkh[0]; kh[1] = nkh[1];
        kl[0] = nkl[0]; kl[1] = nkl[1];
    }

    // combine: lanes (xor 16, 32 merge the lgrp partials), then waves via LDS
    #pragma unroll
    for (int mt = 0; mt < 4; ++mt) {
        float m_ = M[mt], l_ = Ls[mt];
        float mo = __shfl_xor(m_, 16), lo_ = __shfl_xor(l_, 16);
        float mm = fmaxf(m_, mo);
        l_ = l_ * __expf(m_ - mm) + lo_ * __expf(mo - mm);
        m_ = mm;
        mo = __shfl_xor(m_, 32); lo_ = __shfl_xor(l_, 32);
        mm = fmaxf(m_, mo);
        l_ = l_ * __expf(m_ - mm) + lo_ * __expf(mo - mm);
        m_ = mm;
        if (lgrp == 0) { redM[w][mt][lrow] = m_; redL[w][mt][lrow] = l_; }
    }
    __syncthreads();
    float Mf[4], Li[4];
    #pragma unroll
    for (int mt = 0; mt < 4; ++mt) {
        float m0 = redM[0][mt][lrow], m1 = redM[1][mt][lrow];
        float m2 = redM[2][mt][lrow], m3 = redM[3][mt][lrow];
        float mm = fmaxf(fmaxf(m0, m1), fmaxf(m2, m3));
        float ls = redL[0][mt][lrow] * __expf(m0 - mm)
                 + redL[1][mt][lrow] * __expf(m1 - mm)
                 + redL[2][mt][lrow] * __expf(m2 - mm)
                 + redL[3][mt][lrow] * __expf(m3 - mm);
        Mf[mt] = mm;
        Li[mt] = 1.f / ls;
    }

    // ---------- phase 2: recompute S^T, emit P, PV direct from C-frag ----------
    // S^T C-frag (m=lane&15, n=4*lgrp+reg) IS the 16x16x16f16 A-frag layout
    // (row=lane&15, k=4*(lane>>4)+j): P never leaves the lane, no LDS exchange.
    f32x4 accO[4][4];
    #pragma unroll
    for (int mt = 0; mt < 4; ++mt)
        #pragma unroll
        for (int dt = 0; dt < 4; ++dt)
            accO[mt][dt] = (f32x4){0.f, 0.f, 0.f, 0.f};

    float* scbase = score + ((size_t)(h * L_ + qb * 64)) * L_;

    h16x8 vb[2];
    #pragma unroll
    for (int ks = 0; ks < 2; ++ks) {
        kh[ks] = *(const s16x8*)(khs + KFO(0, ks));
        kl[ks] = *(const s16x8*)(kls + KFO(0, ks));
        vb[ks] = *(const h16x8*)(vfs + KFO(0, ks));
    }
    #pragma unroll 2
    for (int kt = 0; kt < NKT; ++kt) {
        s16x8 nkh[2], nkl[2];
        h16x8 nvb[2];
        const int ktn = (kt + 1) & 63;
        #pragma unroll
        for (int ks = 0; ks < 2; ++ks) {
            nkh[ks] = *(const s16x8*)(khs + KFO(ktn, ks));
            nkl[ks] = *(const s16x8*)(kls + KFO(ktn, ks));
            nvb[ks] = *(const h16x8*)(vfs + KFO(ktn, ks));
        }
        h16x4 b0 = __builtin_shufflevector(vb[0], vb[0], 0, 1, 2, 3);   // dt=0
        h16x4 b1 = __builtin_shufflevector(vb[0], vb[0], 4, 5, 6, 7);   // dt=1
        h16x4 b2 = __builtin_shufflevector(vb[1], vb[1], 0, 1, 2, 3);   // dt=2
        h16x4 b3 = __builtin_shufflevector(vb[1], vb[1], 4, 5, 6, 7);   // dt=3
        #pragma unroll
        for (int mt = 0; mt < 4; ++mt) {
            f32x4 acc = {0.f, 0.f, 0.f, 0.f};
            #pragma unroll
            for (int ks = 0; ks < 2; ++ks) {
                acc = __builtin_amdgcn_mfma_f32_16x16x32_bf16(kh[ks], bQh[mt][ks], acc, 0, 0, 0);
                acc = __builtin_amdgcn_mfma_f32_16x16x32_bf16(kh[ks], bQl[mt][ks], acc, 0, 0, 0);
                acc = __builtin_amdgcn_mfma_f32_16x16x32_bf16(kl[ks], bQh[mt][ks], acc, 0, 0, 0);
            }
            f32x4 p;
            p.x = __expf(acc.x - Mf[mt]) * Li[mt];
            p.y = __expf(acc.y - Mf[mt]) * Li[mt];
            p.z = __expf(acc.z - Mf[mt]) * Li[mt];
            p.w = __expf(acc.w - Mf[mt]) * Li[mt];
            *(f32x4*)(scbase + (size_t)(16 * mt + lrow) * L_ + kt * 64 + 16 * w + 4 * lgrp) = p;
            h16x4 pa;
            pa[0] = (_Float16)p.x; pa[1] = (_Float16)p.y;
            pa[2] = (_Float16)p.z; pa[3] = (_Float16)p.w;
            accO[mt][0] = __builtin_amdgcn_mfma_f32_16x16x16f16(pa, b0, accO[mt][0], 0, 0, 0);
            accO[mt][1] = __builtin_amdgcn_mfma_f32_16x16x16f16(pa, b1, accO[mt][1], 0, 0, 0);
            accO[mt][2] = __builtin_amdgcn_mfma_f32_16x16x16f16(pa, b2, accO[mt][2], 0, 0, 0);
            accO[mt][3] = __builtin_amdgcn_mfma_f32_16x16x16f16(pa, b3, accO[mt][3], 0, 0, 0);
        }
        kh[0] = nkh[0]; kh[1] = nkh[1];
        kl[0] = nkl[0]; kl[1] = nkl[1];
        vb[0] = nvb[0]; vb[1] = nvb[1];
    }

    // ---------- cross-wave O reduction (only block-wide sync in the kernel) ----
    // C-frag of 16x16x16: d = 16*dt + lrow, m = 16*mt + 4*lgrp + reg
    for (int w2 = 0; w2 < 4; ++w2) {
        if (w == w2) {
            #pragma unroll
            for (int mt = 0; mt < 4; ++mt)
                #pragma unroll
                for (int dt = 0; dt < 4; ++dt) {
                    int d = 16 * dt + lrow;
                    #pragma unroll
                    for (int r2 = 0; r2 < 4; ++r2) {
                        int m = 16 * mt + 4 * lgrp + r2;
                        if (w2 == 0) Ored[m][d] = accO[mt][dt][r2];
                        else         Ored[m][d] += accO[mt][dt][r2];
                    }
                }
        }
        __syncthreads();
    }
    float* obase = out + ((size_t)(h * L_ + qb * 64)) * D_;
    #pragma unroll
    for (int i = 0; i < 4; ++i) {
        int off = tid * 4 + 1024 * i;
        int m = off >> 6, c = off & 63;
        f32x4 x = {Ored[m][c], Ored[m][c + 1], Ored[m][c + 2], Ored[m][c + 3]};
        *(f32x4*)(obase + off) = x;
    }
}

extern "C" void kernel_launch(void* const* d_in, const int* in_sizes, int n_in,
                              void* d_out, int out_size, void* d_ws, size_t ws_size,
                              hipStream_t stream) {
    const float* q = (const float*)d_in[0];
    const float* k = (const float*)d_in[1];
    const float* v = (const float*)d_in[2];
    float* out = (float*)d_out;
    float* score = out + (size_t)H_ * L_ * D_;          // tuple order: (out, score)

    short*    khi = (short*)d_ws;                                  // 8 MB
    short*    klo = (short*)((char*)d_ws + ((size_t)8 << 20));     // 8 MB
    _Float16* vfr = (_Float16*)((char*)d_ws + ((size_t)16 << 20)); // 8 MB

    kfrag_kernel<<<dim3(NKT, H_), 256, 0, stream>>>(k, khi, klo);
    vfrag_kernel<<<dim3(NKT, H_), 256, 0, stream>>>(v, vfr);
    attn_kernel<<<dim3(64, H_), 256, 0, stream>>>(q, khi, klo, vfr, out, score);
}